// Round 9
// baseline (78.030 us; speedup 1.0000x reference)
//
#include <hip/hip_runtime.h>
#include <math.h>

// Chamfer distance: B=16, N=M=2048, D=3, fp32.
// R8 post-mortem: occupancy levers both directions are null-to-negative;
//   two self-consistent budget models remain: (A) fused ~5-6us + ~20us fixed
//   graph overhead -> R3 IS the roofline; (B) fused ~12-18us latency-bound +
//   small overhead -> ~10us headroom. Our kernels never appear in top-5
//   (masked by the 40us harness fills), so this round is a MEASUREMENT PROBE:
//   exact R3 kernel, but chamfer_fused launched TWICE (idempotent — second
//   launch recomputes identical bsum; stream-serialized; sum reads after).
//   Delta vs R3's 65.7 = fused + ~2us node overhead.
//   Decision rule: dur <= 74 -> Story A, declare roofline next round (single
//   launch); dur >= 78 -> Story B, attack fused kernel latency.
// Kernel body = R3 verbatim (best measured, 65.7us): SPT=8, padded LDS,
//   scalar prologues, unroll 1, (256,2), plain bsum store + 1-block sum.

typedef float v2f __attribute__((ext_vector_type(2)));

#define NPTS   2048
#define NCOMBO 32          // 2 dirs x 16 batches
#define SRCB   64          // src points per block
#define SPT    8           // src points per thread
#define OPPT   64          // opp points scanned per thread
#define NBLK   (NCOMBO * 32)
#define PAD(i) ((i) + (((i) >> 6) << 2))   // +4 words per 64 -> bank spread

__device__ __forceinline__ v2f pkfma(v2f a, v2f b, v2f c) {
#if __has_builtin(__builtin_elementwise_fma)
    return __builtin_elementwise_fma(a, b, c);
#else
    v2f d; d.x = fmaf(a.x, b.x, c.x); d.y = fmaf(a.y, b.y, c.y); return d;
#endif
}

__global__ __launch_bounds__(256, 2) void chamfer_fused(
    const float* __restrict__ preds,
    const float* __restrict__ tgts,
    float* __restrict__ bsum)
{
    __shared__ __align__(16) float qx[2176];   // 2048 + 128 pad words
    __shared__ __align__(16) float qy[2176];
    __shared__ __align__(16) float qz[2176];
    __shared__ __align__(16) float qw[2176];
    __shared__ float sm[4 * SRCB];             // per-wave partial minima

    const int combo = blockIdx.x & (NCOMBO - 1);
    const int chunk = blockIdx.x >> 5;         // 0..31
    const int dir   = combo >> 4;
    const int b     = combo & 15;

    const float* src = (dir ? tgts : preds) + (size_t)b * NPTS * 3;
    const float* opp = (dir ? preds : tgts) + (size_t)b * NPTS * 3;

    // Stage all 2048 opposing points (SoA, padded; |y|^2 in qw)
    #pragma unroll
    for (int p = 0; p < NPTS / 256; p++) {
        const int i = threadIdx.x + 256 * p;
        const float y0 = opp[3 * i + 0];
        const float y1 = opp[3 * i + 1];
        const float y2 = opp[3 * i + 2];
        const int pi = PAD(i);
        qx[pi] = y0;
        qy[pi] = y1;
        qz[pi] = y2;
        qw[pi] = y0 * y0 + y1 * y1 + y2 * y2;
    }

    const int q = threadIdx.x >> 3;   // opp range [64q, 64q+64)
    const int c = threadIdx.x & 7;    // src ownership group

    // 8 src points per thread; nn = -2*x duplicated for packed math
    v2f nn0[SPT], nn1[SPT], nn2[SPT];
    float m[SPT];
    #pragma unroll
    for (int k = 0; k < SPT; k++) {
        const int s = chunk * SRCB + c * SPT + k;
        const float a0 = -2.0f * src[3 * s + 0];
        const float a1 = -2.0f * src[3 * s + 1];
        const float a2 = -2.0f * src[3 * s + 2];
        nn0[k] = (v2f){a0, a0};
        nn1[k] = (v2f){a1, a1};
        nn2[k] = (v2f){a2, a2};
        m[k]   = INFINITY;
    }
    __syncthreads();

    const int base = q * 68;          // PAD(q*64); 16B-aligned
    #pragma unroll 1
    for (int g = 0; g < OPPT / 4; g++) {
        const float4 X = *(const float4*)&qx[base + 4 * g];
        const float4 Y = *(const float4*)&qy[base + 4 * g];
        const float4 Z = *(const float4*)&qz[base + 4 * g];
        const float4 W = *(const float4*)&qw[base + 4 * g];
        const v2f Xa = {X.x, X.y}, Xb = {X.z, X.w};
        const v2f Ya = {Y.x, Y.y}, Yb = {Y.z, Y.w};
        const v2f Za = {Z.x, Z.y}, Zb = {Z.z, Z.w};
        const v2f Wa = {W.x, W.y}, Wb = {W.z, W.w};
        #pragma unroll
        for (int k = 0; k < SPT; k++) {
            const v2f sa = pkfma(nn0[k], Xa, pkfma(nn1[k], Ya, pkfma(nn2[k], Za, Wa)));
            m[k] = fminf(fminf(m[k], sa.x), sa.y);        // v_min3_f32
            const v2f sb = pkfma(nn0[k], Xb, pkfma(nn1[k], Yb, pkfma(nn2[k], Zb, Wb)));
            m[k] = fminf(fminf(m[k], sb.x), sb.y);        // v_min3_f32
        }
    }

    // Min over the 32 q-groups: 8 in-wave q's via shfl_xor (bits 3..5 of lane),
    // then the 4 waves via 1KB LDS.
    #pragma unroll
    for (int k = 0; k < SPT; k++) {
        float v = m[k];
        v = fminf(v, __shfl_xor(v, 8, 64));
        v = fminf(v, __shfl_xor(v, 16, 64));
        v = fminf(v, __shfl_xor(v, 32, 64));
        m[k] = v;
    }
    const int lane = threadIdx.x & 63;
    const int wid  = threadIdx.x >> 6;
    if (lane < 8) {
        #pragma unroll
        for (int k = 0; k < SPT; k++)
            sm[wid * SRCB + c * SPT + k] = m[k];
    }
    __syncthreads();

    // Wave 0: finalize 64 src minima, add |x|^2, block-sum, ONE plain store.
    if (threadIdx.x < 64) {
        const int off = (threadIdx.x & 7) * SPT + (threadIdx.x >> 3);
        float mn = fminf(fminf(sm[off],            sm[SRCB + off]),
                         fminf(sm[2 * SRCB + off], sm[3 * SRCB + off]));
        const int s = chunk * SRCB + off;
        const float x0 = src[3 * s + 0];
        const float x1 = src[3 * s + 1];
        const float x2 = src[3 * s + 2];
        float val = x0 * x0 + x1 * x1 + x2 * x2 + mn;
        #pragma unroll
        for (int o = 32; o > 0; o >>= 1)
            val += __shfl_down(val, o, 64);
        if (threadIdx.x == 0) bsum[blockIdx.x] = val;
    }
}

__global__ __launch_bounds__(256) void chamfer_sum(
    const float* __restrict__ bsum,
    float* __restrict__ out)
{
    __shared__ float wsum[4];

    float val = bsum[threadIdx.x]         + bsum[threadIdx.x + 256]
              + bsum[threadIdx.x + 512]   + bsum[threadIdx.x + 768];

    #pragma unroll
    for (int o = 32; o > 0; o >>= 1)
        val += __shfl_down(val, o, 64);

    const int lane = threadIdx.x & 63;
    const int wid  = threadIdx.x >> 6;
    if (lane == 0) wsum[wid] = val;
    __syncthreads();
    if (threadIdx.x == 0)
        out[0] = wsum[0] + wsum[1] + wsum[2] + wsum[3];
}

extern "C" void kernel_launch(void* const* d_in, const int* in_sizes, int n_in,
                              void* d_out, int out_size, void* d_ws, size_t ws_size,
                              hipStream_t stream) {
    const float* preds = (const float*)d_in[0];
    const float* tgts  = (const float*)d_in[1];
    float* out  = (float*)d_out;
    float* bsum = (float*)d_ws;   // 1024 floats

    // PROBE: launch fused twice (idempotent). Delta vs R3 = fused + node ovh.
    chamfer_fused<<<NBLK, 256, 0, stream>>>(preds, tgts, bsum);
    chamfer_fused<<<NBLK, 256, 0, stream>>>(preds, tgts, bsum);
    chamfer_sum<<<1, 256, 0, stream>>>(bsum, out);
}

// Round 10
// 67.377 us; speedup vs baseline: 1.1581x; 1.1581x over previous
//
#include <hip/hip_runtime.h>
#include <math.h>

// Chamfer distance: B=16, N=M=2048, D=3, fp32. Fused main kernel + tiny reduce.
// R9 probe resolved the budget fork: double-launch delta = 12.3us -> fused
//   kernel ~10.5us vs 3.4us VALU floor (Story B: real headroom in-kernel).
// LDS-pipe accounting: R3 = 64 ds_read_b128 (12cy) + 32 ds_write_b32 (6cy)
//   = 960 cyc/wave x 16 waves/CU = 6.4us/CU -> LDS is the binding pipe.
// This round cuts LDS traffic with SPT/occupancy/inner-loop UNchanged:
//   1) qw deleted: |y|^2 computed in-register per g-iter (6 pk-VALU shared
//      across 8 k's). Reads 64->48/thread, LDS 35.8->26.5 KB.
//   2) staging writes via R5's static float4 deswizzle, stored as b128 into
//      the padded layout (pts 4t..4t+3 never cross a pad boundary; PAD(4t)
//      16B-aligned) -> 6 ds_write_b128 instead of 24 ds_write_b32.
//   New LDS budget 648 cyc/wave (-33%); VALU +9% on a less-loaded pipe.
// Block = (combo, 64-src chunk), 1024 blocks; q = tid>>3 scans opp
//   [64q,64q+64), c = tid&7 owns src pts c*8..c*8+7. Read banks unchanged:
//   68q = 4q mod 32 -> 8 q's/wave cover all 32 banks, conflict-free.

typedef float v2f __attribute__((ext_vector_type(2)));

#define NPTS   2048
#define NCOMBO 32          // 2 dirs x 16 batches
#define SRCB   64          // src points per block
#define SPT    8           // src points per thread
#define OPPT   64          // opp points scanned per thread
#define NBLK   (NCOMBO * 32)
#define PAD(i) ((i) + (((i) >> 6) << 2))   // +4 words per 64 -> bank spread

__device__ __forceinline__ v2f pkfma(v2f a, v2f b, v2f c) {
#if __has_builtin(__builtin_elementwise_fma)
    return __builtin_elementwise_fma(a, b, c);
#else
    v2f d; d.x = fmaf(a.x, b.x, c.x); d.y = fmaf(a.y, b.y, c.y); return d;
#endif
}

__global__ __launch_bounds__(256, 2) void chamfer_fused(
    const float* __restrict__ preds,
    const float* __restrict__ tgts,
    float* __restrict__ bsum)
{
    // 3 x 2176 x 4 B + 1 KB sm = 27136 B -> >=5 blocks/CU by LDS.
    __shared__ __align__(16) float qx[2176];   // 2048 + 128 pad words
    __shared__ __align__(16) float qy[2176];
    __shared__ __align__(16) float qz[2176];
    __shared__ float sm[4 * SRCB];             // per-wave partial minima

    const int combo = blockIdx.x & (NCOMBO - 1);
    const int chunk = blockIdx.x >> 5;         // 0..31
    const int dir   = combo >> 4;
    const int b     = combo & 15;

    const float* src = (dir ? tgts : preds) + (size_t)b * NPTS * 3;
    const float* opp = (dir ? preds : tgts) + (size_t)b * NPTS * 3;

    // Stage all 2048 opposing points (SoA, padded). 3 float4 loads = 4
    // interleaved xyz pts (STATIC deswizzle, no scratch); pts 4t..4t+3 are
    // contiguous in the padded layout -> one ds_write_b128 per array.
    const float4* opp4 = (const float4*)opp;
    #pragma unroll
    for (int p = 0; p < 2; p++) {
        const int t  = threadIdx.x + 256 * p;   // pts 4t..4t+3
        const float4 A = opp4[3 * t + 0];       // x0 y0 z0 x1
        const float4 B = opp4[3 * t + 1];       // y1 z1 x2 y2
        const float4 C = opp4[3 * t + 2];       // z2 x3 y3 z3
        const float4 xv = {A.x, A.w, B.z, C.y};
        const float4 yv = {A.y, B.x, B.w, C.z};
        const float4 zv = {A.z, B.y, C.x, C.w};
        const int pi = PAD(4 * t);              // 16B-aligned, no pad crossing
        *(float4*)&qx[pi] = xv;
        *(float4*)&qy[pi] = yv;
        *(float4*)&qz[pi] = zv;
    }

    const int q = threadIdx.x >> 3;   // opp range [64q, 64q+64)
    const int c = threadIdx.x & 7;    // src ownership group

    // 8 src points per thread; nn = -2*x duplicated for packed math
    v2f nn0[SPT], nn1[SPT], nn2[SPT];
    float m[SPT];
    #pragma unroll
    for (int k = 0; k < SPT; k++) {
        const int s = chunk * SRCB + c * SPT + k;
        const float a0 = -2.0f * src[3 * s + 0];
        const float a1 = -2.0f * src[3 * s + 1];
        const float a2 = -2.0f * src[3 * s + 2];
        nn0[k] = (v2f){a0, a0};
        nn1[k] = (v2f){a1, a1};
        nn2[k] = (v2f){a2, a2};
        m[k]   = INFINITY;
    }
    __syncthreads();

    const int base = q * 68;          // PAD(q*64); 16B-aligned
    #pragma unroll 1
    for (int g = 0; g < OPPT / 4; g++) {
        const float4 X = *(const float4*)&qx[base + 4 * g];
        const float4 Y = *(const float4*)&qy[base + 4 * g];
        const float4 Z = *(const float4*)&qz[base + 4 * g];
        const v2f Xa = {X.x, X.y}, Xb = {X.z, X.w};
        const v2f Ya = {Y.x, Y.y}, Yb = {Y.z, Y.w};
        const v2f Za = {Z.x, Z.y}, Zb = {Z.z, Z.w};
        // |y|^2 in-register (replaces the qw b128 read), shared over 8 k's
        const v2f Wa = pkfma(Za, Za, pkfma(Ya, Ya, Xa * Xa));
        const v2f Wb = pkfma(Zb, Zb, pkfma(Yb, Yb, Xb * Xb));
        #pragma unroll
        for (int k = 0; k < SPT; k++) {
            const v2f sa = pkfma(nn0[k], Xa, pkfma(nn1[k], Ya, pkfma(nn2[k], Za, Wa)));
            m[k] = fminf(fminf(m[k], sa.x), sa.y);        // v_min3_f32
            const v2f sb = pkfma(nn0[k], Xb, pkfma(nn1[k], Yb, pkfma(nn2[k], Zb, Wb)));
            m[k] = fminf(fminf(m[k], sb.x), sb.y);        // v_min3_f32
        }
    }

    // Min over the 32 q-groups: 8 in-wave q's via shfl_xor (bits 3..5 of lane),
    // then the 4 waves via 1KB LDS.
    #pragma unroll
    for (int k = 0; k < SPT; k++) {
        float v = m[k];
        v = fminf(v, __shfl_xor(v, 8, 64));
        v = fminf(v, __shfl_xor(v, 16, 64));
        v = fminf(v, __shfl_xor(v, 32, 64));
        m[k] = v;
    }
    const int lane = threadIdx.x & 63;
    const int wid  = threadIdx.x >> 6;
    if (lane < 8) {
        #pragma unroll
        for (int k = 0; k < SPT; k++)
            sm[wid * SRCB + c * SPT + k] = m[k];
    }
    __syncthreads();

    // Wave 0: finalize 64 src minima, add |x|^2, block-sum, ONE plain store.
    if (threadIdx.x < 64) {
        const int off = (threadIdx.x & 7) * SPT + (threadIdx.x >> 3);
        float mn = fminf(fminf(sm[off],            sm[SRCB + off]),
                         fminf(sm[2 * SRCB + off], sm[3 * SRCB + off]));
        const int s = chunk * SRCB + off;
        const float x0 = src[3 * s + 0];
        const float x1 = src[3 * s + 1];
        const float x2 = src[3 * s + 2];
        float val = x0 * x0 + x1 * x1 + x2 * x2 + mn;
        #pragma unroll
        for (int o = 32; o > 0; o >>= 1)
            val += __shfl_down(val, o, 64);
        if (threadIdx.x == 0) bsum[blockIdx.x] = val;
    }
}

__global__ __launch_bounds__(256) void chamfer_sum(
    const float* __restrict__ bsum,
    float* __restrict__ out)
{
    __shared__ float wsum[4];

    float val = bsum[threadIdx.x]         + bsum[threadIdx.x + 256]
              + bsum[threadIdx.x + 512]   + bsum[threadIdx.x + 768];

    #pragma unroll
    for (int o = 32; o > 0; o >>= 1)
        val += __shfl_down(val, o, 64);

    const int lane = threadIdx.x & 63;
    const int wid  = threadIdx.x >> 6;
    if (lane == 0) wsum[wid] = val;
    __syncthreads();
    if (threadIdx.x == 0)
        out[0] = wsum[0] + wsum[1] + wsum[2] + wsum[3];
}

extern "C" void kernel_launch(void* const* d_in, const int* in_sizes, int n_in,
                              void* d_out, int out_size, void* d_ws, size_t ws_size,
                              hipStream_t stream) {
    const float* preds = (const float*)d_in[0];
    const float* tgts  = (const float*)d_in[1];
    float* out  = (float*)d_out;
    float* bsum = (float*)d_ws;   // 1024 floats

    chamfer_fused<<<NBLK, 256, 0, stream>>>(preds, tgts, bsum);
    chamfer_sum<<<1, 256, 0, stream>>>(bsum, out);
}

// Round 11
// 66.855 us; speedup vs baseline: 1.1672x; 1.0078x over previous
//
#include <hip/hip_runtime.h>
#include <math.h>

// Chamfer distance: B=16, N=M=2048, D=3, fp32. Fused main kernel + tiny reduce.
// R10 post-mortem: LDS-traffic cut (-33%) null; occupancy nulls (R6/R8);
//   R9 probe says fused ~10.5us vs ~4-5us VALU model. Remaining suspect that
//   is source-fixable: __builtin_elementwise_fma on v2f may SCALARIZE to
//   2x v_fma_f32 (never verified in .s) -> inner loop 1.75x VALU cost, which
//   closes the 2x gap. This round pins the packed op with inline asm
//   v_pk_fma_f32 (VOP3P, 64-bit VGPR pairs via "v" constraint on v2f).
//   Base = R3 verbatim (best measured, 65.7us); ONLY pkfma's body changes.
// Pre-committed: dur ~62.5-64.5 -> scalarization was real, keep pushing VALU;
//   null 65.5-67.5 -> all in-kernel pipes individually nulled -> ROOFLINE
//   next round; mild regression -> revert, same conclusion.

typedef float v2f __attribute__((ext_vector_type(2)));

#define NPTS   2048
#define NCOMBO 32          // 2 dirs x 16 batches
#define SRCB   64          // src points per block
#define SPT    8           // src points per thread
#define OPPT   64          // opp points scanned per thread
#define NBLK   (NCOMBO * 32)
#define PAD(i) ((i) + (((i) >> 6) << 2))   // +4 words per 64 -> bank spread

__device__ __forceinline__ v2f pkfma(v2f a, v2f b, v2f c) {
    // D.lo = a.lo*b.lo + c.lo ; D.hi = a.hi*b.hi + c.hi  (one VOP3P inst)
    v2f d;
    asm("v_pk_fma_f32 %0, %1, %2, %3" : "=v"(d) : "v"(a), "v"(b), "v"(c));
    return d;
}

__global__ __launch_bounds__(256, 2) void chamfer_fused(
    const float* __restrict__ preds,
    const float* __restrict__ tgts,
    float* __restrict__ bsum)
{
    __shared__ __align__(16) float qx[2176];   // 2048 + 128 pad words
    __shared__ __align__(16) float qy[2176];
    __shared__ __align__(16) float qz[2176];
    __shared__ __align__(16) float qw[2176];
    __shared__ float sm[4 * SRCB];             // per-wave partial minima

    const int combo = blockIdx.x & (NCOMBO - 1);
    const int chunk = blockIdx.x >> 5;         // 0..31
    const int dir   = combo >> 4;
    const int b     = combo & 15;

    const float* src = (dir ? tgts : preds) + (size_t)b * NPTS * 3;
    const float* opp = (dir ? preds : tgts) + (size_t)b * NPTS * 3;

    // Stage all 2048 opposing points (SoA, padded; |y|^2 in qw)
    #pragma unroll
    for (int p = 0; p < NPTS / 256; p++) {
        const int i = threadIdx.x + 256 * p;
        const float y0 = opp[3 * i + 0];
        const float y1 = opp[3 * i + 1];
        const float y2 = opp[3 * i + 2];
        const int pi = PAD(i);
        qx[pi] = y0;
        qy[pi] = y1;
        qz[pi] = y2;
        qw[pi] = y0 * y0 + y1 * y1 + y2 * y2;
    }

    const int q = threadIdx.x >> 3;   // opp range [64q, 64q+64)
    const int c = threadIdx.x & 7;    // src ownership group

    // 8 src points per thread; nn = -2*x duplicated for packed math
    v2f nn0[SPT], nn1[SPT], nn2[SPT];
    float m[SPT];
    #pragma unroll
    for (int k = 0; k < SPT; k++) {
        const int s = chunk * SRCB + c * SPT + k;
        const float a0 = -2.0f * src[3 * s + 0];
        const float a1 = -2.0f * src[3 * s + 1];
        const float a2 = -2.0f * src[3 * s + 2];
        nn0[k] = (v2f){a0, a0};
        nn1[k] = (v2f){a1, a1};
        nn2[k] = (v2f){a2, a2};
        m[k]   = INFINITY;
    }
    __syncthreads();

    const int base = q * 68;          // PAD(q*64); 16B-aligned
    #pragma unroll 1
    for (int g = 0; g < OPPT / 4; g++) {
        const float4 X = *(const float4*)&qx[base + 4 * g];
        const float4 Y = *(const float4*)&qy[base + 4 * g];
        const float4 Z = *(const float4*)&qz[base + 4 * g];
        const float4 W = *(const float4*)&qw[base + 4 * g];
        const v2f Xa = {X.x, X.y}, Xb = {X.z, X.w};
        const v2f Ya = {Y.x, Y.y}, Yb = {Y.z, Y.w};
        const v2f Za = {Z.x, Z.y}, Zb = {Z.z, Z.w};
        const v2f Wa = {W.x, W.y}, Wb = {W.z, W.w};
        #pragma unroll
        for (int k = 0; k < SPT; k++) {
            const v2f sa = pkfma(nn0[k], Xa, pkfma(nn1[k], Ya, pkfma(nn2[k], Za, Wa)));
            m[k] = fminf(fminf(m[k], sa.x), sa.y);        // v_min3_f32
            const v2f sb = pkfma(nn0[k], Xb, pkfma(nn1[k], Yb, pkfma(nn2[k], Zb, Wb)));
            m[k] = fminf(fminf(m[k], sb.x), sb.y);        // v_min3_f32
        }
    }

    // Min over the 32 q-groups: 8 in-wave q's via shfl_xor (bits 3..5 of lane),
    // then the 4 waves via 1KB LDS.
    #pragma unroll
    for (int k = 0; k < SPT; k++) {
        float v = m[k];
        v = fminf(v, __shfl_xor(v, 8, 64));
        v = fminf(v, __shfl_xor(v, 16, 64));
        v = fminf(v, __shfl_xor(v, 32, 64));
        m[k] = v;
    }
    const int lane = threadIdx.x & 63;
    const int wid  = threadIdx.x >> 6;
    if (lane < 8) {
        #pragma unroll
        for (int k = 0; k < SPT; k++)
            sm[wid * SRCB + c * SPT + k] = m[k];
    }
    __syncthreads();

    // Wave 0: finalize 64 src minima, add |x|^2, block-sum, ONE plain store.
    if (threadIdx.x < 64) {
        const int off = (threadIdx.x & 7) * SPT + (threadIdx.x >> 3);
        float mn = fminf(fminf(sm[off],            sm[SRCB + off]),
                         fminf(sm[2 * SRCB + off], sm[3 * SRCB + off]));
        const int s = chunk * SRCB + off;
        const float x0 = src[3 * s + 0];
        const float x1 = src[3 * s + 1];
        const float x2 = src[3 * s + 2];
        float val = x0 * x0 + x1 * x1 + x2 * x2 + mn;
        #pragma unroll
        for (int o = 32; o > 0; o >>= 1)
            val += __shfl_down(val, o, 64);
        if (threadIdx.x == 0) bsum[blockIdx.x] = val;
    }
}

__global__ __launch_bounds__(256) void chamfer_sum(
    const float* __restrict__ bsum,
    float* __restrict__ out)
{
    __shared__ float wsum[4];

    float val = bsum[threadIdx.x]         + bsum[threadIdx.x + 256]
              + bsum[threadIdx.x + 512]   + bsum[threadIdx.x + 768];

    #pragma unroll
    for (int o = 32; o > 0; o >>= 1)
        val += __shfl_down(val, o, 64);

    const int lane = threadIdx.x & 63;
    const int wid  = threadIdx.x >> 6;
    if (lane == 0) wsum[wid] = val;
    __syncthreads();
    if (threadIdx.x == 0)
        out[0] = wsum[0] + wsum[1] + wsum[2] + wsum[3];
}

extern "C" void kernel_launch(void* const* d_in, const int* in_sizes, int n_in,
                              void* d_out, int out_size, void* d_ws, size_t ws_size,
                              hipStream_t stream) {
    const float* preds = (const float*)d_in[0];
    const float* tgts  = (const float*)d_in[1];
    float* out  = (float*)d_out;
    float* bsum = (float*)d_ws;   // 1024 floats

    chamfer_fused<<<NBLK, 256, 0, stream>>>(preds, tgts, bsum);
    chamfer_sum<<<1, 256, 0, stream>>>(bsum, out);
}